// Round 6
// baseline (62.348 us; speedup 1.0000x reference)
//
#include <hip/hip_runtime.h>
#include <hip/hip_bf16.h>
#include <math.h>

#define NROW 8192
#define DIM  128
#define BM   64
#define BN   128
#define NTILES 4160         // sum_{tr<128} (64 - (tr>>1))
#define NT4    (NTILES * 4) // per-wave results

typedef __bf16 bf16x8 __attribute__((ext_vector_type(8)));
typedef float  f32x4  __attribute__((ext_vector_type(4)));
typedef float  f32x2  __attribute__((ext_vector_type(2)));

#define G2      369.3299304675746f    /* 256 * log2(e): logits in base-2 */
#define NEGBIG  (-3.0e38f)
#define NOFF    2000.0f               /* neg-class offset: class-by-value */

// ---- Kernel A: normalize rows -> bf16 ----
__global__ __launch_bounds__(256)
void prep_kernel(const float* __restrict__ f, __hip_bfloat16* __restrict__ fhi) {
    int row  = blockIdx.x * 4 + (threadIdx.x >> 6);
    int lane = threadIdx.x & 63;
    float2 v = ((const float2*)(f + (size_t)row * DIM))[lane];
    float ss = v.x * v.x + v.y * v.y;
    #pragma unroll
    for (int off = 32; off; off >>= 1) ss += __shfl_xor(ss, off, 64);
    float inv = 1.0f / fmaxf(sqrtf(ss), 1e-12f);
    __hip_bfloat162 hv;
    hv.x = __float2bfloat16(v.x * inv);
    hv.y = __float2bfloat16(v.y * inv);
    ((__hip_bfloat162*)(fhi + (size_t)row * DIM))[lane] = hv;
}

// first linear bid of row-tile tr (tc starts at tr>>1)
__device__ __forceinline__ int tstart(int tr) {
    int m = tr >> 1;
    int f = m * m - ((tr & 1) ? 0 : m);
    return 64 * tr - f;
}

// ---- Kernel B: MFMA sim + lean fused two-pass LSE, per-wave results ----
__global__ __launch_bounds__(256, 4)
void sim_kernel(const __hip_bfloat16* __restrict__ fhi,
                const int* __restrict__ lab,
                float4* __restrict__ blockRes) {
    const int tid  = threadIdx.x;
    const int w    = tid >> 6;
    const int lane = tid & 63;
    const int lrow = lane & 15;
    const int lk   = lane >> 4;

    // triangular decode: bid -> (tr, tc), tc >= tr>>1
    int bid = blockIdx.x;
    float sa = fmaxf(16384.f - 4.f * (float)bid, 0.f);
    int tr = 128 - (int)sqrtf(sa);
    if (tr > 127) tr = 127;
    if (tr < 0) tr = 0;
    while (tr > 0 && bid < tstart(tr)) --tr;
    while (bid >= tstart(tr + 1)) ++tr;
    const int tc = (tr >> 1) + (bid - tstart(tr));

    const int rowBase = tr * BM;
    const int colBase = tc * BN;

    __shared__ __align__(16) char smem[24 * 1024]; // A[64][64] + B[128][64] bf16
    __shared__ int labA[BM];
    __shared__ int labB[BN];

    if (tid < BM)            labA[tid] = lab[rowBase + tid];
    else if (tid < BM + BN)  labB[tid - BM] = lab[colBase + (tid - BM)];

    f32x4 acc[4][2];
    #pragma unroll
    for (int mi = 0; mi < 4; ++mi)
        #pragma unroll
        for (int ni = 0; ni < 2; ++ni) acc[mi][ni] = (f32x4){0.f, 0.f, 0.f, 0.f};

    const int ncol0 = w * 32;                     // 1x4 wave grid: 64x32 per wave
    const int rsub = lane >> 3;                   // row within 8-row segment
    const int kbs  = 16 * ((lane & 7) ^ rsub);    // pre-swizzled source byte

    for (int kc = 0; kc < 2; ++kc) {   // two K=64 chunks
        #pragma unroll
        for (int t = 0; t < 6; ++t) {
            int seg = w * 6 + t;          // 0..23 segments of 1KB (A:0-7, B:8-23)
            char* ldsb = smem + seg * 1024;
            int grow = (seg < 8) ? (rowBase + (seg & 7) * 8 + rsub)
                                 : (colBase + (seg - 8) * 8 + rsub);
            const char* g = (const char*)fhi + (size_t)grow * 256 + kc * 128 + kbs;
            __builtin_amdgcn_global_load_lds(
                (const __attribute__((address_space(1))) void*)g,
                (__attribute__((address_space(3))) void*)ldsb, 16, 0, 0);
        }
        __syncthreads();   // drains vmcnt

        const char* As = smem;
        const char* Bs = smem + 8192;
        #pragma unroll
        for (int c = 0; c < 2; ++c) {
            int kb = c * 64 + lk * 16;
            bf16x8 bfr[2];
            #pragma unroll
            for (int ni = 0; ni < 2; ++ni) {
                int rb = ncol0 + ni * 16 + lrow;
                bfr[ni] = *(const bf16x8*)(Bs + rb * 128 + (kb ^ ((rb & 7) << 4)));
            }
            #pragma unroll
            for (int mi = 0; mi < 4; ++mi) {
                int ra = mi * 16 + lrow;
                bf16x8 afr = *(const bf16x8*)(As + ra * 128 + (kb ^ ((ra & 7) << 4)));
                #pragma unroll
                for (int ni = 0; ni < 2; ++ni)
                    acc[mi][ni] = __builtin_amdgcn_mfma_f32_16x16x32_bf16(afr, bfr[ni], acc[mi][ni], 0, 0, 0);
            }
        }
        if (kc == 0) __syncthreads();   // protect LDS reuse (none needed after kc=1)
    }

    // ---- pass A: packed quadratic logits + per-wave maxes ----
    const f32x2 G2v   = {G2, G2};
    const f32x2 Pposv = {-2.0f * G2, -2.0f * G2};
    const f32x2 Qposv = {0.9375f * G2, 0.9375f * G2};
    const f32x2 Qnegv = {-0.0625f * G2 - NOFF, -0.0625f * G2 - NOFF};
    const f32x2 mq    = {-0.25f, -0.25f};
    float mall = NEGBIG, mneg = NEGBIG;

    int lbv[2];
    #pragma unroll
    for (int ni = 0; ni < 2; ++ni) lbv[ni] = labB[ncol0 + ni * 16 + lrow];

#define PASS_A(EDGEF)                                                          \
    _Pragma("unroll")                                                          \
    for (int mi = 0; mi < 4; ++mi) {                                           \
        int4 la4 = *(const int4*)&labA[mi * 16 + lk * 4];                      \
        const int la[4] = {la4.x, la4.y, la4.z, la4.w};                        \
        _Pragma("unroll")                                                      \
        for (int ni = 0; ni < 2; ++ni) {                                       \
            const int lb = lbv[ni];                                            \
            f32x4 v = acc[mi][ni];                                             \
            f32x2 s01 = {v.x, v.y}, s23 = {v.z, v.w};                          \
            f32x2 xp01 = __builtin_elementwise_fma(G2v, s01 * s01,             \
                           __builtin_elementwise_fma(Pposv, s01, Qposv));      \
            f32x2 xp23 = __builtin_elementwise_fma(G2v, s23 * s23,             \
                           __builtin_elementwise_fma(Pposv, s23, Qposv));      \
            f32x2 t01 = __builtin_elementwise_max(s01, mq);                    \
            f32x2 t23 = __builtin_elementwise_max(s23, mq);                    \
            f32x2 xn01 = __builtin_elementwise_fma(G2v, t01 * t01, Qnegv);     \
            f32x2 xn23 = __builtin_elementwise_fma(G2v, t23 * t23, Qnegv);     \
            const float xpv[4] = {xp01.x, xp01.y, xp23.x, xp23.y};             \
            const float xnv[4] = {xn01.x, xn01.y, xn23.x, xn23.y};             \
            _Pragma("unroll")                                                  \
            for (int r = 0; r < 4; ++r) {                                      \
                bool pos = (la[r] == lb);                                      \
                float x = pos ? xpv[r] : xnv[r];                               \
                if (EDGEF) {                                                   \
                    int ig = rowBase + mi * 16 + lk * 4 + r;                   \
                    int jg = colBase + ncol0 + ni * 16 + lrow;                 \
                    x = (jg > ig) ? x : NEGBIG;                                \
                }                                                              \
                mall = fmaxf(mall, x);                                         \
                mneg = fmaxf(mneg, pos ? NEGBIG : x);                          \
                acc[mi][ni][r] = x;                                            \
            }                                                                  \
        }                                                                      \
    }

    if (tc == (tr >> 1)) { PASS_A(true) } else { PASS_A(false) }
#undef PASS_A

    // ---- wave max reduce (no barrier) ----
    #pragma unroll
    for (int off = 32; off; off >>= 1) {
        mall = fmaxf(mall, __shfl_xor(mall, off, 64));
        mneg = fmaxf(mneg, __shfl_xor(mneg, off, 64));
    }
    const float Mp  = (mall > -1000.f) ? mall : 0.f;       // pos-empty sentinel
    const float Mn2 = (mneg > -2500.f) ? mneg : -4000.f;   // neg-empty sentinel

    // ---- pass B: packed subs/adds, 2 exp2/elem ----
    const f32x2 Mpv = {Mp, Mp}, Mnv = {Mn2, Mn2};
    f32x2 sp2 = {0.f, 0.f}, sn2 = {0.f, 0.f};
    #pragma unroll
    for (int mi = 0; mi < 4; ++mi)
        #pragma unroll
        for (int ni = 0; ni < 2; ++ni) {
            f32x4 v = acc[mi][ni];
            #pragma unroll
            for (int h = 0; h < 2; ++h) {
                f32x2 p = h ? (f32x2){v.z, v.w} : (f32x2){v.x, v.y};
                f32x2 dp = p - Mpv;                         // pk_add
                sp2 += (f32x2){__builtin_amdgcn_exp2f(dp.x),
                               __builtin_amdgcn_exp2f(dp.y)};
                float xm0 = (p.x > -1000.f) ? NEGBIG : p.x;
                float xm1 = (p.y > -1000.f) ? NEGBIG : p.y;
                f32x2 dn = (f32x2){xm0, xm1} - Mnv;
                sn2 += (f32x2){__builtin_amdgcn_exp2f(dn.x),
                               __builtin_amdgcn_exp2f(dn.y)};
            }
        }
    float sp = sp2.x + sp2.y, sn = sn2.x + sn2.y;

    // ---- wave sum reduce + per-wave write (no block reduce) ----
    #pragma unroll
    for (int off = 32; off; off >>= 1) {
        sp += __shfl_xor(sp, off, 64);
        sn += __shfl_xor(sn, off, 64);
    }
    if (lane == 0) blockRes[bid * 4 + w] = make_float4(Mp, sp, Mn2, sn);
}

// ---- Kernel C: merge per-wave (m,s) pairs (base-2) + softplus ----
__device__ __forceinline__ void merge2(float& m, float& s, float mo, float so) {
    float M = fmaxf(m, mo);
    s = s * __builtin_amdgcn_exp2f(m - M) + so * __builtin_amdgcn_exp2f(mo - M);
    m = M;
}

__global__ __launch_bounds__(256)
void finalize_kernel(const float4* __restrict__ blockRes, float* __restrict__ out) {
    __shared__ float red[4][4];
    int tid = threadIdx.x;
    float mpa[2] = {NEGBIG, NEGBIG}, spa[2] = {0.f, 0.f};
    float mna[2] = {NEGBIG, NEGBIG}, sna[2] = {0.f, 0.f};
    for (int i = tid; i < NT4; i += 512) {   // 2-way ILP streams
        float4 v = blockRes[i];
        merge2(mpa[0], spa[0], v.x, v.y);
        merge2(mna[0], sna[0], v.z, v.w);
        int j = i + 256;
        if (j < NT4) {
            float4 u = blockRes[j];
            merge2(mpa[1], spa[1], u.x, u.y);
            merge2(mna[1], sna[1], u.z, u.w);
        }
    }
    float mp = mpa[0], sp = spa[0], mn = mna[0], sn = sna[0];
    merge2(mp, sp, mpa[1], spa[1]);
    merge2(mn, sn, mna[1], sna[1]);
    #pragma unroll
    for (int off = 32; off; off >>= 1) {
        float mo = __shfl_xor(mp, off, 64), so = __shfl_xor(sp, off, 64);
        merge2(mp, sp, mo, so);
        float mo2 = __shfl_xor(mn, off, 64), so2 = __shfl_xor(sn, off, 64);
        merge2(mn, sn, mo2, so2);
    }
    int wv = tid >> 6;
    if ((tid & 63) == 0) {
        red[wv][0] = mp; red[wv][1] = sp; red[wv][2] = mn; red[wv][3] = sn;
    }
    __syncthreads();
    if (tid == 0) {
        mp = red[0][0]; sp = red[0][1]; mn = red[0][2]; sn = red[0][3];
        #pragma unroll
        for (int q = 1; q < 4; ++q) {
            merge2(mp, sp, red[q][0], red[q][1]);
            merge2(mn, sn, red[q][2], red[q][3]);
        }
        const double LN2 = 0.6931471805599453;
        double lse_p = ((double)mp + log2((double)sp)) * LN2;
        double lse_n = ((double)mn + (double)NOFF + log2((double)sn)) * LN2;
        double xx = lse_p + lse_n;
        double r = (xx > 30.0) ? xx : log1p(exp(xx));
        out[0] = (float)r;
    }
}

extern "C" void kernel_launch(void* const* d_in, const int* in_sizes, int n_in,
                              void* d_out, int out_size, void* d_ws, size_t ws_size,
                              hipStream_t stream) {
    const float* f   = (const float*)d_in[0];
    const int*   lab = (const int*)d_in[1];
    float*  out      = (float*)d_out;

    __hip_bfloat16* fhi = (__hip_bfloat16*)d_ws;                     // 2 MB
    float4* blockRes    = (float4*)((char*)d_ws + 4u * 1024 * 1024); // 16640 float4

    prep_kernel<<<NROW / 4, 256, 0, stream>>>(f, fhi);
    sim_kernel<<<NTILES, 256, 0, stream>>>(fhi, lab, blockRes);
    finalize_kernel<<<1, 256, 0, stream>>>(blockRes, out);
}

// Round 7
// 44.723 us; speedup vs baseline: 1.3941x; 1.3941x over previous
//
#include <hip/hip_runtime.h>
#include <hip/hip_bf16.h>
#include <math.h>

#define NROW 8192
#define DIM  128
#define BM   64
#define BN   128
#define NTILES 4160         // sum_{tr<128} (64 - (tr>>1))
#define NT4    (NTILES * 4) // per-wave results = 16640 = 32 * 520
#define NRED   32           // reduce blocks
#define PERRED (NT4 / NRED) // 520

typedef __bf16 bf16x8 __attribute__((ext_vector_type(8)));
typedef float  f32x4  __attribute__((ext_vector_type(4)));
typedef float  f32x2  __attribute__((ext_vector_type(2)));

#define G2      369.3299304675746f    /* 256 * log2(e): logits in base-2 */
#define NEGBIG  (-3.0e38f)
#define NOFF    2000.0f               /* neg-class offset: class-by-value */

// ---- Kernel A: normalize rows -> bf16 ----
__global__ __launch_bounds__(256)
void prep_kernel(const float* __restrict__ f, __hip_bfloat16* __restrict__ fhi) {
    int row  = blockIdx.x * 4 + (threadIdx.x >> 6);
    int lane = threadIdx.x & 63;
    float2 v = ((const float2*)(f + (size_t)row * DIM))[lane];
    float ss = v.x * v.x + v.y * v.y;
    #pragma unroll
    for (int off = 32; off; off >>= 1) ss += __shfl_xor(ss, off, 64);
    float inv = 1.0f / fmaxf(sqrtf(ss), 1e-12f);
    __hip_bfloat162 hv;
    hv.x = __float2bfloat16(v.x * inv);
    hv.y = __float2bfloat16(v.y * inv);
    ((__hip_bfloat162*)(fhi + (size_t)row * DIM))[lane] = hv;
}

// first linear bid of row-tile tr (tc starts at tr>>1)
__device__ __forceinline__ int tstart(int tr) {
    int m = tr >> 1;
    int f = m * m - ((tr & 1) ? 0 : m);
    return 64 * tr - f;
}

// ---- Kernel B: MFMA sim + lean fused two-pass LSE, per-wave results ----
__global__ __launch_bounds__(256, 4)
void sim_kernel(const __hip_bfloat16* __restrict__ fhi,
                const int* __restrict__ lab,
                float4* __restrict__ blockRes) {
    const int tid  = threadIdx.x;
    const int w    = tid >> 6;
    const int lane = tid & 63;
    const int lrow = lane & 15;
    const int lk   = lane >> 4;

    // triangular decode: bid -> (tr, tc), tc >= tr>>1
    int bid = blockIdx.x;
    float sa = fmaxf(16384.f - 4.f * (float)bid, 0.f);
    int tr = 128 - (int)sqrtf(sa);
    if (tr > 127) tr = 127;
    if (tr < 0) tr = 0;
    while (tr > 0 && bid < tstart(tr)) --tr;
    while (bid >= tstart(tr + 1)) ++tr;
    const int tc = (tr >> 1) + (bid - tstart(tr));

    const int rowBase = tr * BM;
    const int colBase = tc * BN;

    __shared__ __align__(16) char smem[24 * 1024]; // A[64][64] + B[128][64] bf16
    __shared__ int labA[BM];
    __shared__ int labB[BN];

    if (tid < BM)            labA[tid] = lab[rowBase + tid];
    else if (tid < BM + BN)  labB[tid - BM] = lab[colBase + (tid - BM)];

    f32x4 acc[4][2];
    #pragma unroll
    for (int mi = 0; mi < 4; ++mi)
        #pragma unroll
        for (int ni = 0; ni < 2; ++ni) acc[mi][ni] = (f32x4){0.f, 0.f, 0.f, 0.f};

    const int ncol0 = w * 32;                     // 1x4 wave grid: 64x32 per wave
    const int rsub = lane >> 3;                   // row within 8-row segment
    const int kbs  = 16 * ((lane & 7) ^ rsub);    // pre-swizzled source byte

    for (int kc = 0; kc < 2; ++kc) {   // two K=64 chunks
        #pragma unroll
        for (int t = 0; t < 6; ++t) {
            int seg = w * 6 + t;          // 0..23 segments of 1KB (A:0-7, B:8-23)
            char* ldsb = smem + seg * 1024;
            int grow = (seg < 8) ? (rowBase + (seg & 7) * 8 + rsub)
                                 : (colBase + (seg - 8) * 8 + rsub);
            const char* g = (const char*)fhi + (size_t)grow * 256 + kc * 128 + kbs;
            __builtin_amdgcn_global_load_lds(
                (const __attribute__((address_space(1))) void*)g,
                (__attribute__((address_space(3))) void*)ldsb, 16, 0, 0);
        }
        __syncthreads();   // drains vmcnt

        const char* As = smem;
        const char* Bs = smem + 8192;
        #pragma unroll
        for (int c = 0; c < 2; ++c) {
            int kb = c * 64 + lk * 16;
            bf16x8 bfr[2];
            #pragma unroll
            for (int ni = 0; ni < 2; ++ni) {
                int rb = ncol0 + ni * 16 + lrow;
                bfr[ni] = *(const bf16x8*)(Bs + rb * 128 + (kb ^ ((rb & 7) << 4)));
            }
            #pragma unroll
            for (int mi = 0; mi < 4; ++mi) {
                int ra = mi * 16 + lrow;
                bf16x8 afr = *(const bf16x8*)(As + ra * 128 + (kb ^ ((ra & 7) << 4)));
                #pragma unroll
                for (int ni = 0; ni < 2; ++ni)
                    acc[mi][ni] = __builtin_amdgcn_mfma_f32_16x16x32_bf16(afr, bfr[ni], acc[mi][ni], 0, 0, 0);
            }
        }
        if (kc == 0) __syncthreads();   // protect LDS reuse before chunk 1 staging
    }

    // ---- pass A: packed quadratic logits + per-wave maxes ----
    const f32x2 G2v   = {G2, G2};
    const f32x2 Pposv = {-2.0f * G2, -2.0f * G2};
    const f32x2 Qposv = {0.9375f * G2, 0.9375f * G2};
    const f32x2 Qnegv = {-0.0625f * G2 - NOFF, -0.0625f * G2 - NOFF};
    const f32x2 mq    = {-0.25f, -0.25f};
    float mall = NEGBIG, mneg = NEGBIG;

    int lbv[2];
    #pragma unroll
    for (int ni = 0; ni < 2; ++ni) lbv[ni] = labB[ncol0 + ni * 16 + lrow];

#define PASS_A(EDGEF)                                                          \
    _Pragma("unroll")                                                          \
    for (int mi = 0; mi < 4; ++mi) {                                           \
        int4 la4 = *(const int4*)&labA[mi * 16 + lk * 4];                      \
        const int la[4] = {la4.x, la4.y, la4.z, la4.w};                        \
        _Pragma("unroll")                                                      \
        for (int ni = 0; ni < 2; ++ni) {                                       \
            const int lb = lbv[ni];                                            \
            f32x4 v = acc[mi][ni];                                             \
            f32x2 s01 = {v.x, v.y}, s23 = {v.z, v.w};                          \
            f32x2 xp01 = __builtin_elementwise_fma(G2v, s01 * s01,             \
                           __builtin_elementwise_fma(Pposv, s01, Qposv));      \
            f32x2 xp23 = __builtin_elementwise_fma(G2v, s23 * s23,             \
                           __builtin_elementwise_fma(Pposv, s23, Qposv));      \
            f32x2 t01 = __builtin_elementwise_max(s01, mq);                    \
            f32x2 t23 = __builtin_elementwise_max(s23, mq);                    \
            f32x2 xn01 = __builtin_elementwise_fma(G2v, t01 * t01, Qnegv);     \
            f32x2 xn23 = __builtin_elementwise_fma(G2v, t23 * t23, Qnegv);     \
            const float xpv[4] = {xp01.x, xp01.y, xp23.x, xp23.y};             \
            const float xnv[4] = {xn01.x, xn01.y, xn23.x, xn23.y};             \
            _Pragma("unroll")                                                  \
            for (int r = 0; r < 4; ++r) {                                      \
                bool pos = (la[r] == lb);                                      \
                float x = pos ? xpv[r] : xnv[r];                               \
                if (EDGEF) {                                                   \
                    int ig = rowBase + mi * 16 + lk * 4 + r;                   \
                    int jg = colBase + ncol0 + ni * 16 + lrow;                 \
                    x = (jg > ig) ? x : NEGBIG;                                \
                }                                                              \
                mall = fmaxf(mall, x);                                         \
                mneg = fmaxf(mneg, pos ? NEGBIG : x);                          \
                acc[mi][ni][r] = x;                                            \
            }                                                                  \
        }                                                                      \
    }

    if (tc == (tr >> 1)) { PASS_A(true) } else { PASS_A(false) }
#undef PASS_A

    // ---- wave max reduce (no barrier) ----
    #pragma unroll
    for (int off = 32; off; off >>= 1) {
        mall = fmaxf(mall, __shfl_xor(mall, off, 64));
        mneg = fmaxf(mneg, __shfl_xor(mneg, off, 64));
    }
    const float Mp  = (mall > -1000.f) ? mall : 0.f;       // pos-empty sentinel
    const float Mn2 = (mneg > -2500.f) ? mneg : -4000.f;   // neg-empty sentinel

    // ---- pass B: packed subs/adds, 2 exp2/elem ----
    const f32x2 Mpv = {Mp, Mp}, Mnv = {Mn2, Mn2};
    f32x2 sp2 = {0.f, 0.f}, sn2 = {0.f, 0.f};
    #pragma unroll
    for (int mi = 0; mi < 4; ++mi)
        #pragma unroll
        for (int ni = 0; ni < 2; ++ni) {
            f32x4 v = acc[mi][ni];
            #pragma unroll
            for (int h = 0; h < 2; ++h) {
                f32x2 p = h ? (f32x2){v.z, v.w} : (f32x2){v.x, v.y};
                f32x2 dp = p - Mpv;
                sp2 += (f32x2){__builtin_amdgcn_exp2f(dp.x),
                               __builtin_amdgcn_exp2f(dp.y)};
                float xm0 = (p.x > -1000.f) ? NEGBIG : p.x;
                float xm1 = (p.y > -1000.f) ? NEGBIG : p.y;
                f32x2 dn = (f32x2){xm0, xm1} - Mnv;
                sn2 += (f32x2){__builtin_amdgcn_exp2f(dn.x),
                               __builtin_amdgcn_exp2f(dn.y)};
            }
        }
    float sp = sp2.x + sp2.y, sn = sn2.x + sn2.y;

    // ---- wave sum reduce + per-wave write (no block reduce) ----
    #pragma unroll
    for (int off = 32; off; off >>= 1) {
        sp += __shfl_xor(sp, off, 64);
        sn += __shfl_xor(sn, off, 64);
    }
    if (lane == 0) blockRes[bid * 4 + w] = make_float4(Mp, sp, Mn2, sn);
}

// ---- merge helper: (m,s) pairs represent s * 2^m ----
__device__ __forceinline__ void merge2(float& m, float& s, float mo, float so) {
    float M = fmaxf(m, mo);
    s = s * __builtin_amdgcn_exp2f(m - M) + so * __builtin_amdgcn_exp2f(mo - M);
    m = M;
}

// ---- Kernel C1: parallel tree reduce 16640 -> 32 ----
__global__ __launch_bounds__(256)
void reduce_kernel(const float4* __restrict__ in, float4* __restrict__ partial) {
    __shared__ float red[4][4];
    const int tid  = threadIdx.x;
    const int base = blockIdx.x * PERRED;
    float mp = NEGBIG, sp = 0.f, mn = NEGBIG, sn = 0.f;
    for (int i = tid; i < PERRED; i += 256) {
        float4 v = in[base + i];
        merge2(mp, sp, v.x, v.y);
        merge2(mn, sn, v.z, v.w);
    }
    #pragma unroll
    for (int off = 32; off; off >>= 1) {
        float mo = __shfl_xor(mp, off, 64), so = __shfl_xor(sp, off, 64);
        merge2(mp, sp, mo, so);
        float mo2 = __shfl_xor(mn, off, 64), so2 = __shfl_xor(sn, off, 64);
        merge2(mn, sn, mo2, so2);
    }
    const int wv = tid >> 6;
    if ((tid & 63) == 0) {
        red[wv][0] = mp; red[wv][1] = sp; red[wv][2] = mn; red[wv][3] = sn;
    }
    __syncthreads();
    if (tid == 0) {
        mp = red[0][0]; sp = red[0][1]; mn = red[0][2]; sn = red[0][3];
        #pragma unroll
        for (int q = 1; q < 4; ++q) {
            merge2(mp, sp, red[q][0], red[q][1]);
            merge2(mn, sn, red[q][2], red[q][3]);
        }
        partial[blockIdx.x] = make_float4(mp, sp, mn, sn);
    }
}

// ---- Kernel C2: merge 32 partials + softplus ----
__global__ __launch_bounds__(64)
void finalize_kernel(const float4* __restrict__ partial, float* __restrict__ out) {
    const int lane = threadIdx.x;
    float mp = NEGBIG, sp = 0.f, mn = NEGBIG, sn = 0.f;
    if (lane < NRED) {
        float4 v = partial[lane];
        mp = v.x; sp = v.y; mn = v.z; sn = v.w;
    }
    #pragma unroll
    for (int off = 32; off; off >>= 1) {
        float mo = __shfl_xor(mp, off, 64), so = __shfl_xor(sp, off, 64);
        merge2(mp, sp, mo, so);
        float mo2 = __shfl_xor(mn, off, 64), so2 = __shfl_xor(sn, off, 64);
        merge2(mn, sn, mo2, so2);
    }
    if (lane == 0) {
        const double LN2 = 0.6931471805599453;
        double lse_p = ((double)mp + log2((double)sp)) * LN2;
        double lse_n = ((double)mn + (double)NOFF + log2((double)sn)) * LN2;
        double xx = lse_p + lse_n;
        double r = (xx > 30.0) ? xx : log1p(exp(xx));
        out[0] = (float)r;
    }
}

extern "C" void kernel_launch(void* const* d_in, const int* in_sizes, int n_in,
                              void* d_out, int out_size, void* d_ws, size_t ws_size,
                              hipStream_t stream) {
    const float* f   = (const float*)d_in[0];
    const int*   lab = (const int*)d_in[1];
    float*  out      = (float*)d_out;

    __hip_bfloat16* fhi = (__hip_bfloat16*)d_ws;                     // 2 MB
    float4* blockRes    = (float4*)((char*)d_ws + 4u * 1024 * 1024); // 16640 float4
    float4* partial     = (float4*)((char*)d_ws + 8u * 1024 * 1024); // 32 float4

    prep_kernel<<<NROW / 4, 256, 0, stream>>>(f, fhi);
    sim_kernel<<<NTILES, 256, 0, stream>>>(fhi, lab, blockRes);
    reduce_kernel<<<NRED, 256, 0, stream>>>(blockRes, partial);
    finalize_kernel<<<1, 64, 0, stream>>>(partial, out);
}